// Round 6
// baseline (118.299 us; speedup 1.0000x reference)
//
#include <hip/hip_runtime.h>

typedef __attribute__((ext_vector_type(8))) short short8;
typedef __attribute__((ext_vector_type(8))) __bf16 bf16x8;
typedef __attribute__((ext_vector_type(4))) float f32x4;
typedef __attribute__((ext_vector_type(4))) float float4v;
typedef __attribute__((ext_vector_type(4))) unsigned short ushort4v;
typedef __attribute__((ext_vector_type(2))) unsigned uint2v;

#define AS1 __attribute__((address_space(1)))
#define AS3 __attribute__((address_space(3)))

#define BATCH 4
#define SEQ 1024
#define DM 1024
#define NH 16
#define DKH 64
#define MROWS (BATCH * SEQ) /* 4096 */
#define N3 (3 * DM)         /* 3072 */

static __device__ __forceinline__ unsigned short f2bf(float f) {
  unsigned u = __builtin_bit_cast(unsigned, f);
  u += 0x7FFFu + ((u >> 16) & 1u);
  return (unsigned short)(u >> 16);
}
static __device__ __forceinline__ float bf2f(unsigned short h) {
  return __builtin_bit_cast(float, ((unsigned)h) << 16);
}
static __device__ __forceinline__ f32x4 mfma16(short8 a, short8 b, f32x4 c) {
  return __builtin_amdgcn_mfma_f32_16x16x32_bf16(
      __builtin_bit_cast(bf16x8, a), __builtin_bit_cast(bf16x8, b), c, 0, 0, 0);
}

// ---------------- fp32 -> bf16 convert (x, Wq, Wk, Wv concat, Wo) ----------------
__global__ __launch_bounds__(256) void convert_kernel(
    const float* __restrict__ x, const float* __restrict__ wq,
    const float* __restrict__ wk, const float* __restrict__ wv,
    const float* __restrict__ wo, unsigned short* __restrict__ xb,
    unsigned short* __restrict__ wqkv, unsigned short* __restrict__ wob) {
  size_t i4 = ((size_t)blockIdx.x * 256 + threadIdx.x) * 4;
  const size_t SZX = (size_t)MROWS * DM;  // 4M
  const size_t SZW = (size_t)DM * DM;     // 1M
  const float* src;
  unsigned short* dst;
  size_t off;
  if (i4 < SZX) {
    src = x; dst = xb; off = i4;
  } else if (i4 < SZX + SZW) {
    src = wq; dst = wqkv; off = i4 - SZX;
  } else if (i4 < SZX + 2 * SZW) {
    src = wk; dst = wqkv + SZW; off = i4 - SZX - SZW;
  } else if (i4 < SZX + 3 * SZW) {
    src = wv; dst = wqkv + 2 * SZW; off = i4 - SZX - 2 * SZW;
  } else {
    src = wo; dst = wob; off = i4 - SZX - 3 * SZW;
  }
  float4v v = *(const float4v*)(src + off);
  ushort4v o;
  o.x = f2bf(v.x); o.y = f2bf(v.y); o.z = f2bf(v.z); o.w = f2bf(v.w);
  *(ushort4v*)(dst + off) = o;
}

// ---------------- bf16 GEMM: C[M][N] = A[M][K] * B[N][K]^T ----------------
// 128x128 tile, BK=64, 4 waves (2x2 of 64x64), global_load_lds + XOR swizzle.
static __device__ __forceinline__ void store_c(float* p, float v) { *p = v; }
static __device__ __forceinline__ void store_c(unsigned short* p, float v) { *p = f2bf(v); }

template <typename OutT>
__global__ __launch_bounds__(256) void gemm_bt(
    const unsigned short* __restrict__ A, const unsigned short* __restrict__ B,
    OutT* __restrict__ C, int M, int N, int K) {
  __shared__ char sA[16384];
  __shared__ char sB[16384];
  const int tid = threadIdx.x, w = tid >> 6, lane = tid & 63;
  const int g = lane >> 4, r = lane & 15;
  const int m0 = blockIdx.y * 128, n0 = blockIdx.x * 128;
  const int wm = (w >> 1) * 64, wn = (w & 1) * 64;
  f32x4 acc[4][4] = {};
  for (int k0 = 0; k0 < K; k0 += 64) {
#pragma unroll
    for (int c = 0; c < 4; ++c) {
      int p = c * 4096 + tid * 16;            // linear LDS byte pos
      int o = p ^ (((p >> 7) & 7) << 4);      // inverse-swizzled logical pos
      int row = o >> 7, colb = o & 127;
      const char* ga = (const char*)(A + (size_t)(m0 + row) * K + k0) + colb;
      const char* gb = (const char*)(B + (size_t)(n0 + row) * K + k0) + colb;
      __builtin_amdgcn_global_load_lds((const AS1 void*)ga,
                                       (AS3 void*)(sA + c * 4096 + (w << 10)), 16, 0, 0);
      __builtin_amdgcn_global_load_lds((const AS1 void*)gb,
                                       (AS3 void*)(sB + c * 4096 + (w << 10)), 16, 0, 0);
    }
    __syncthreads();
#pragma unroll
    for (int kk = 0; kk < 2; ++kk) {
      short8 af[4], bfr[4];
#pragma unroll
      for (int i = 0; i < 4; ++i) {
        int ra = wm + i * 16 + r;
        af[i] = *(const short8*)(sA + (((ra << 7) + (kk << 6) + (g << 4)) ^ ((ra & 7) << 4)));
        int rb = wn + i * 16 + r;
        bfr[i] = *(const short8*)(sB + (((rb << 7) + (kk << 6) + (g << 4)) ^ ((rb & 7) << 4)));
      }
#pragma unroll
      for (int i = 0; i < 4; ++i)
#pragma unroll
        for (int j = 0; j < 4; ++j) acc[i][j] = mfma16(af[i], bfr[j], acc[i][j]);
    }
    __syncthreads();
  }
#pragma unroll
  for (int i = 0; i < 4; ++i)
#pragma unroll
    for (int j = 0; j < 4; ++j)
#pragma unroll
      for (int jj = 0; jj < 4; ++jj) {
        int row = m0 + wm + i * 16 + g * 4 + jj;
        int col = n0 + wn + j * 16 + r;
        store_c(&C[(size_t)row * N + col], acc[i][j][jj]);
      }
}

// ---------------- RoPE on Q,K + relayout to (b,h,s,d); Q scaled by 1/8 ----------------
__global__ __launch_bounds__(256) void rope_qk(const unsigned short* __restrict__ cf,
                                               unsigned short* __restrict__ qb,
                                               unsigned short* __restrict__ kb) {
  int i = blockIdx.x * 256 + threadIdx.x;  // 2M pairs
  int k = i & 31, h = (i >> 5) & 15, s = (i >> 9) & 1023, b = i >> 19;
  float freq = __expf(-(float)k * 0.28782313662425572f);  // 10000^(-k/32)
  float ang = (float)s * freq;
  float sn, cs;
  __sincosf(ang, &sn, &cs);
  const unsigned short* src = cf + (size_t)(b * SEQ + s) * N3 + h * DKH + 2 * k;
  float qe = bf2f(src[0]), qo = bf2f(src[1]);
  float ke = bf2f(src[DM]), ko = bf2f(src[DM + 1]);
  float q0 = (qe * cs - qo * sn) * 0.125f;
  float q1 = (qe * sn + qo * cs) * 0.125f;
  float k0 = ke * cs - ko * sn;
  float k1 = ke * sn + ko * cs;
  size_t dsto = (size_t)((b * NH + h) * SEQ + s) * DKH + 2 * k;
  *(unsigned*)(qb + dsto) = (unsigned)f2bf(q0) | ((unsigned)f2bf(q1) << 16);
  *(unsigned*)(kb + dsto) = (unsigned)f2bf(k0) | ((unsigned)f2bf(k1) << 16);
}

// ---------------- V transpose: cf V slice (b,s,h,d) -> vt (b,h,d,s) ----------------
__global__ __launch_bounds__(256) void transpose_v(const unsigned short* __restrict__ cf,
                                                   unsigned short* __restrict__ vt) {
  __shared__ unsigned short tile[64][72];  // [s][d], stride 72 keeps 16B alignment
  int bh = blockIdx.y, b = bh >> 4, h = bh & 15, s0 = blockIdx.x * 64;
  int t = threadIdx.x, row = t >> 2, c0 = (t & 3) * 16;
  const unsigned short* src = cf + (size_t)(b * SEQ + s0 + row) * N3 + 2 * DM + h * DKH + c0;
  short8 v0 = *(const short8*)src;
  short8 v1 = *(const short8*)(src + 8);
  *(short8*)&tile[row][c0] = v0;
  *(short8*)&tile[row][c0 + 8] = v1;
  __syncthreads();
  unsigned short* dst = vt + ((size_t)bh * DKH + row) * SEQ + s0 + c0;
  short8 o0, o1;
#pragma unroll
  for (int j = 0; j < 8; ++j) o0[j] = (short)tile[c0 + j][row];
#pragma unroll
  for (int j = 0; j < 8; ++j) o1[j] = (short)tile[c0 + 8 + j][row];
  *(short8*)dst = o0;
  *(short8*)(dst + 8) = o1;
}

// ---------------- causal flash attention (v5: 2-wave blocks, 32-row pairs) ----------
// grid (16, 64), 128 threads (2 waves). Block bx pairs 32-row q-tiles qtlo=bx and
// qthi=31-bx: per-block work = 17 tile-computations for EVERY bx (balanced), and
// 1024 blocks -> 4 blocks/CU x 2 waves = 8 waves/CU across 4 independent barrier
// domains (phase diversity to hide the per-iter dependent chain).
// Swapped-operand math identical to v4: S/O live q-on-col; per-lane softmax.
__global__ __launch_bounds__(128) void attn_kernel(const unsigned short* __restrict__ qb,
                                                   const unsigned short* __restrict__ kb,
                                                   const unsigned short* __restrict__ vt,
                                                   unsigned short* __restrict__ ob) {
  __shared__ char kl[2][8192];
  __shared__ char vl[2][8192];
  __shared__ unsigned short plds[2][2][1024];  // per-wave P buffers (hi, lo)
  const int bx = blockIdx.x, bh = blockIdx.y, b = bh >> 4, h = bh & 15;
  const int qtlo = bx, qthi = 31 - bx;  // 32-row q-tiles
  const int tid = threadIdx.x, w = tid >> 6, lane = tid & 63;
  const int g = lane >> 4, r = lane & 15;
  const unsigned short* Q = qb + (size_t)bh * SEQ * DKH;
  const char* Kp = (const char*)(kb + (size_t)bh * SEQ * DKH);
  const char* Vp = (const char*)(vt + (size_t)bh * DKH * SEQ);

  // staging geometry: 128 threads cover each 8KB tile in 4 chunks of 2KB
  int pc0 = tid * 16;
  size_t ks[4], vs[4];
#pragma unroll
  for (int c = 0; c < 4; ++c) {
    int p = c * 2048 + pc0;
    int o = p ^ (((p >> 7) & 7) << 4);  // inverse-swizzled logical pos
    int row = o >> 7, colb = o & 127;
    ks[c] = (size_t)row * 128 + colb;
    vs[c] = (size_t)row * 2048 + colb;
  }

#define STAGE_KV(bi, kt)                                                          \
  do {                                                                            \
    const char* kbase = Kp + (size_t)(kt) * 8192;                                 \
    const char* vbase = Vp + (size_t)(kt) * 128;                                  \
    _Pragma("unroll") for (int c = 0; c < 4; ++c) {                               \
      __builtin_amdgcn_global_load_lds((const AS1 void*)(kbase + ks[c]),          \
                                       (AS3 void*)(kl[bi] + c * 2048 + pc0), 16,  \
                                       0, 0);                                     \
      __builtin_amdgcn_global_load_lds((const AS1 void*)(vbase + vs[c]),          \
                                       (AS3 void*)(vl[bi] + c * 2048 + pc0), 16,  \
                                       0, 0);                                     \
    }                                                                             \
  } while (0)

  short8 qfL0, qfL1, qfH0, qfH1;
  {
    int qrL = qtlo * 32 + w * 16 + r;
    int qrH = qthi * 32 + w * 16 + r;
    qfL0 = *(const short8*)(Q + (size_t)qrL * DKH + g * 8);
    qfL1 = *(const short8*)(Q + (size_t)qrL * DKH + 32 + g * 8);
    qfH0 = *(const short8*)(Q + (size_t)qrH * DKH + g * 8);
    qfH1 = *(const short8*)(Q + (size_t)qrH * DKH + 32 + g * 8);
  }
  f32x4 oaccL[4] = {}, oaccH[4] = {};
  float mrunL = -1e30f, lrunL = 0.f, mrunH = -1e30f, lrunH = 0.f;
  const int qgH = qthi * 32 + w * 16 + r;  // this lane's hi q-row (global)
  const int qgL = qtlo * 32 + w * 16 + r;  // this lane's lo q-row (global)
  char* pbH = (char*)&plds[w][0][0];
  char* pbL = (char*)&plds[w][1][0];
  const int nktH = (qthi + 2) >> 1;  // K-tiles covering hi q-tile's causal span
  const int nktL = (qtlo + 2) >> 1;

  STAGE_KV(0, 0);
  __syncthreads();

  for (int kt = 0; kt < nktH; ++kt) {
    if (kt + 1 < nktH) STAGE_KV((kt + 1) & 1, kt + 1);  // prefetch next tile
    const bool doLo = (kt < nktL);
    const char* kb_ = kl[kt & 1];
    const char* vb_ = vl[kt & 1];
    f32x4 sh[4] = {}, sl[4] = {};
#pragma unroll
    for (int nb = 0; nb < 4; ++nb) {
      int ra = nb * 16 + r;
      short8 kf0 = *(const short8*)(kb_ + ((ra * 128 + g * 16) ^ ((ra & 7) << 4)));
      short8 kf1 = *(const short8*)(kb_ + ((ra * 128 + 64 + g * 16) ^ ((ra & 7) << 4)));
      sh[nb] = mfma16(kf0, qfH0, sh[nb]);  // swapped: S[k][q]
      sh[nb] = mfma16(kf1, qfH1, sh[nb]);
      if (doLo) {
        sl[nb] = mfma16(kf0, qfL0, sl[nb]);
        sl[nb] = mfma16(kf1, qfL1, sl[nb]);
      }
    }
    // diagonal masks (last tile of each chain's span): k = kt*64+nb*16+g*4+j
    if (kt == nktH - 1) {
#pragma unroll
      for (int nb = 0; nb < 4; ++nb)
#pragma unroll
        for (int j = 0; j < 4; ++j)
          if (kt * 64 + nb * 16 + g * 4 + j > qgH) sh[nb][j] = -1e30f;
    }
    if (doLo && kt == nktL - 1) {
#pragma unroll
      for (int nb = 0; nb < 4; ++nb)
#pragma unroll
        for (int j = 0; j < 4; ++j)
          if (kt * 64 + nb * 16 + g * 4 + j > qgL) sl[nb][j] = -1e30f;
    }
    // ---- softmax H (per-lane row) ----
    float sclH, sclL = 1.f;
    {
      float a0 = fmaxf(fmaxf(sh[0][0], sh[0][1]), fmaxf(sh[0][2], sh[0][3]));
      float a1 = fmaxf(fmaxf(sh[1][0], sh[1][1]), fmaxf(sh[1][2], sh[1][3]));
      float a2 = fmaxf(fmaxf(sh[2][0], sh[2][1]), fmaxf(sh[2][2], sh[2][3]));
      float a3 = fmaxf(fmaxf(sh[3][0], sh[3][1]), fmaxf(sh[3][2], sh[3][3]));
      float tm = fmaxf(fmaxf(a0, a1), fmaxf(a2, a3));
      tm = fmaxf(tm, __shfl_xor(tm, 16, 64));
      tm = fmaxf(tm, __shfl_xor(tm, 32, 64));
      float mnew = fmaxf(mrunH, tm);
      sclH = __expf(mrunH - mnew);
      mrunH = mnew;
      float ps = 0.f;
#pragma unroll
      for (int nb = 0; nb < 4; ++nb)
#pragma unroll
        for (int j = 0; j < 4; ++j) {
          float p = __expf(sh[nb][j] - mnew);
          sh[nb][j] = p;
          ps += p;
        }
      ps += __shfl_xor(ps, 16, 64);
      ps += __shfl_xor(ps, 32, 64);
      lrunH = lrunH * sclH + ps;
#pragma unroll
      for (int nb = 0; nb < 4; ++nb) {
        uint2v pk;
        pk.x = (unsigned)f2bf(sh[nb][0]) | ((unsigned)f2bf(sh[nb][1]) << 16);
        pk.y = (unsigned)f2bf(sh[nb][2]) | ((unsigned)f2bf(sh[nb][3]) << 16);
        *(uint2v*)(pbH + ((r * 128 + nb * 32 + g * 8) ^ ((r & 7) << 4))) = pk;
      }
    }
    // ---- softmax L ----
    if (doLo) {
      float a0 = fmaxf(fmaxf(sl[0][0], sl[0][1]), fmaxf(sl[0][2], sl[0][3]));
      float a1 = fmaxf(fmaxf(sl[1][0], sl[1][1]), fmaxf(sl[1][2], sl[1][3]));
      float a2 = fmaxf(fmaxf(sl[2][0], sl[2][1]), fmaxf(sl[2][2], sl[2][3]));
      float a3 = fmaxf(fmaxf(sl[3][0], sl[3][1]), fmaxf(sl[3][2], sl[3][3]));
      float tm = fmaxf(fmaxf(a0, a1), fmaxf(a2, a3));
      tm = fmaxf(tm, __shfl_xor(tm, 16, 64));
      tm = fmaxf(tm, __shfl_xor(tm, 32, 64));
      float mnew = fmaxf(mrunL, tm);
      sclL = __expf(mrunL - mnew);
      mrunL = mnew;
      float ps = 0.f;
#pragma unroll
      for (int nb = 0; nb < 4; ++nb)
#pragma unroll
        for (int j = 0; j < 4; ++j) {
          float p = __expf(sl[nb][j] - mnew);
          sl[nb][j] = p;
          ps += p;
        }
      ps += __shfl_xor(ps, 16, 64);
      ps += __shfl_xor(ps, 32, 64);
      lrunL = lrunL * sclL + ps;
#pragma unroll
      for (int nb = 0; nb < 4; ++nb) {
        uint2v pk;
        pk.x = (unsigned)f2bf(sl[nb][0]) | ((unsigned)f2bf(sl[nb][1]) << 16);
        pk.y = (unsigned)f2bf(sl[nb][2]) | ((unsigned)f2bf(sl[nb][3]) << 16);
        *(uint2v*)(pbL + ((r * 128 + nb * 32 + g * 8) ^ ((r & 7) << 4))) = pk;
      }
    }
    // rescale O accumulators (per-lane scalar)
#pragma unroll
    for (int db = 0; db < 4; ++db) {
      f32x4 t = oaccH[db];
      t[0] *= sclH; t[1] *= sclH; t[2] *= sclH; t[3] *= sclH;
      oaccH[db] = t;
      if (doLo) {
        f32x4 u = oaccL[db];
        u[0] *= sclL; u[1] *= sclL; u[2] *= sclL; u[3] *= sclL;
        oaccL[db] = u;
      }
    }
    // P write -> read is same-wave only: drain LDS counter, no block barrier
    asm volatile("s_waitcnt lgkmcnt(0)" ::: "memory");
    __builtin_amdgcn_sched_barrier(0);
    // B-frag of P for this lane's own q-row: P[q=r][k=g*8..], halves at +64B
    short8 pfH0 = *(const short8*)(pbH + ((r * 128 + g * 16) ^ ((r & 7) << 4)));
    short8 pfH1 = *(const short8*)(pbH + ((r * 128 + 64 + g * 16) ^ ((r & 7) << 4)));
    short8 pfL0, pfL1;
    if (doLo) {
      pfL0 = *(const short8*)(pbL + ((r * 128 + g * 16) ^ ((r & 7) << 4)));
      pfL1 = *(const short8*)(pbL + ((r * 128 + 64 + g * 16) ^ ((r & 7) << 4)));
    }
#pragma unroll
    for (int db = 0; db < 4; ++db) {
      int rv = db * 16 + r;
      short8 vf0 = *(const short8*)(vb_ + ((rv * 128 + g * 16) ^ ((rv & 7) << 4)));
      short8 vf1 = *(const short8*)(vb_ + ((rv * 128 + 64 + g * 16) ^ ((rv & 7) << 4)));
      oaccH[db] = mfma16(vf0, pfH0, oaccH[db]);  // swapped: O[d][q]
      oaccH[db] = mfma16(vf1, pfH1, oaccH[db]);
      if (doLo) {
        oaccL[db] = mfma16(vf0, pfL0, oaccL[db]);
        oaccL[db] = mfma16(vf1, pfL1, oaccL[db]);
      }
    }
    __syncthreads();  // staging loads drained + all waves done with buffers
  }
  // epilogue: lane holds O[d=db*16+g*4+j][q=own row]; pack 4 bf16 -> 8B stores
  {
    float invH = 1.f / lrunH;
    unsigned short* orH = ob + (size_t)(b * SEQ + qgH) * DM + h * DKH;
#pragma unroll
    for (int db = 0; db < 4; ++db) {
      uint2v pk;
      pk.x = (unsigned)f2bf(oaccH[db][0] * invH) | ((unsigned)f2bf(oaccH[db][1] * invH) << 16);
      pk.y = (unsigned)f2bf(oaccH[db][2] * invH) | ((unsigned)f2bf(oaccH[db][3] * invH) << 16);
      *(uint2v*)(orH + db * 16 + g * 4) = pk;
    }
    float invL = 1.f / lrunL;
    unsigned short* orL = ob + (size_t)(b * SEQ + qgL) * DM + h * DKH;
#pragma unroll
    for (int db = 0; db < 4; ++db) {
      uint2v pk;
      pk.x = (unsigned)f2bf(oaccL[db][0] * invL) | ((unsigned)f2bf(oaccL[db][1] * invL) << 16);
      pk.y = (unsigned)f2bf(oaccL[db][2] * invL) | ((unsigned)f2bf(oaccL[db][3] * invL) << 16);
      *(uint2v*)(orL + db * 16 + g * 4) = pk;
    }
  }
#undef STAGE_KV
}

extern "C" void kernel_launch(void* const* d_in, const int* in_sizes, int n_in,
                              void* d_out, int out_size, void* d_ws, size_t ws_size,
                              hipStream_t stream) {
  const float* x = (const float*)d_in[0];
  // d_in[1] = token_positions (reference ignores it; positions == arange(S))
  const float* wq = (const float*)d_in[2];
  const float* wk = (const float*)d_in[3];
  const float* wv = (const float*)d_in[4];
  const float* wo = (const float*)d_in[5];
  char* ws = (char*)d_ws;
  unsigned short* xb = (unsigned short*)(ws);                  // 8 MiB
  unsigned short* wqkv = (unsigned short*)(ws + (8u << 20));   // 6 MiB [Wq;Wk;Wv][3072][1024]
  unsigned short* wob = (unsigned short*)(ws + (14u << 20));   // 2 MiB
  unsigned short* cf = (unsigned short*)(ws + (16u << 20));    // 24 MiB QKV gemm out (b,s,3072)
  unsigned short* qbuf = (unsigned short*)(ws + (40u << 20));  // 8 MiB (bh,s,d)
  unsigned short* kbuf = (unsigned short*)(ws + (48u << 20));  // 8 MiB (bh,s,d)
  unsigned short* vtb = (unsigned short*)(ws + (56u << 20));   // 8 MiB (bh,d,s)
  unsigned short* obuf = (unsigned short*)(ws + (64u << 20));  // 8 MiB (b,s,e)
  float* out = (float*)d_out;

  convert_kernel<<<8192, 256, 0, stream>>>(x, wq, wk, wv, wo, xb, wqkv, wob);
  gemm_bt<unsigned short><<<dim3(24, 32), 256, 0, stream>>>(xb, wqkv, cf, MROWS, N3, DM);
  rope_qk<<<8192, 256, 0, stream>>>(cf, qbuf, kbuf);
  transpose_v<<<dim3(16, 64), 256, 0, stream>>>(cf, vtb);
  attn_kernel<<<dim3(16, 64), 128, 0, stream>>>(qbuf, kbuf, vtb, obuf);
  gemm_bt<float><<<dim3(8, 32), 256, 0, stream>>>(obuf, wob, out, MROWS, DM, DM);
}